// Round 2
// baseline (380.528 us; speedup 1.0000x reference)
//
#include <hip/hip_runtime.h>
#include <hip/hip_bf16.h>

// Problem constants
#define BB    8
#define NBB   1024
#define KK    9
#define CC    32
#define CMM   128
#define NTOT  (BB*NBB)        // 8192
#define MM    (NBB*KK)        // 9216 per batch
#define NEG   0.01f
#define EPS   1e-5f
#define L2C   (-2.8853900817779268f)   /* -2*log2(e) */
#define NBLK  256

// Workspace layout (floats) — part/x0/x/h0 eliminated (LDS-resident now)
#define OFF_CWT   0
#define SZ_CWT    (BB*CC*MM/2)            // bf16 in float-slots: 1179648
#define OFF_CFX   (OFF_CWT + SZ_CWT)
#define OFF_CFY   (OFF_CFX + BB*MM)
#define OFF_CF0   (OFF_CFY + BB*MM)
#define OFF_ST    (OFF_CF0 + BB*MM)       // stats: s1[64] then s2[256]

typedef __attribute__((ext_vector_type(8))) short short8;
typedef __attribute__((ext_vector_type(4))) float f32x4;
typedef __attribute__((ext_vector_type(2))) float f32x2;

static __device__ __forceinline__ unsigned short f2bf_rne(float f) {
    __hip_bfloat16 h = __float2bfloat16(f);
    return *reinterpret_cast<unsigned short*>(&h);
}

// ---------------------------------------------------------------------------
// Grid barrier: generation-counter protocol, self-resetting across launches.
// 256 blocks = 1/CU (LDS 61.5 KB <= 160 KB) -> all blocks co-resident.
// Producer side: __threadfence (agent release: wbL2) before arrival;
// consumer side: acquire atomic (invL1/L2) + __threadfence after.
// ---------------------------------------------------------------------------
__device__ unsigned g_cnt[4];
__device__ unsigned g_gen[4];

static __device__ __forceinline__ void grid_sync(int i) {
    __threadfence();
    __syncthreads();
    if (threadIdx.x == 0) {
        unsigned g = __hip_atomic_load(&g_gen[i], __ATOMIC_RELAXED, __HIP_MEMORY_SCOPE_AGENT);
        unsigned a = __hip_atomic_fetch_add(&g_cnt[i], 1u, __ATOMIC_ACQ_REL, __HIP_MEMORY_SCOPE_AGENT);
        if (a == NBLK - 1u) {
            __hip_atomic_store(&g_cnt[i], 0u, __ATOMIC_RELAXED, __HIP_MEMORY_SCOPE_AGENT);
            __hip_atomic_store(&g_gen[i], g + 1u, __ATOMIC_RELEASE, __HIP_MEMORY_SCOPE_AGENT);
        } else {
            while (__hip_atomic_load(&g_gen[i], __ATOMIC_ACQUIRE, __HIP_MEMORY_SCOPE_AGENT) == g)
                __builtin_amdgcn_s_sleep(2);
        }
    }
    __syncthreads();
    __threadfence();
}

// LDS float offsets (62976 B total)
#define L_H0   0               // [32][132] f32 h0 tile (pad 132 breaks banks)
#define L_X    4224            // [32][36]  f32 x tile
#define L_X0   5376            // [32][36]  f32 x0 tile
#define L_SCR  6528            // 9216 f32 scratch: A: kwl+tiles / B: red / E: red2
#define L_TOT  15744

// ---------------------------------------------------------------------------
// One fused kernel. Block b=blk>>5 owns n in [blk*32, blk*32+32).
// Phase A: prep coefs (grid-strided) + convw MFMA (2 waves) -> cwT global
// Phase B: sample — 4 waves split m (2304 each), LDS reduce, leaky, s1 atomics
// Phase D: bn1+W1 mlp (x, h0 in LDS), s2 atomics
// Phase E: bn2+W2 mlp, outputs
// ---------------------------------------------------------------------------
__global__ __launch_bounds__(256) void k_fused(
    const float* __restrict__ pos, const float* __restrict__ wts,
    const float* __restrict__ kpos, const float* __restrict__ kw,
    const float* __restrict__ cg, const float* __restrict__ cb,
    const float* __restrict__ W1, const float* __restrict__ b1,
    const float* __restrict__ g2, const float* __restrict__ bt2,
    const float* __restrict__ W2, const float* __restrict__ b2,
    float* __restrict__ ws, float* __restrict__ out)
{
    __shared__ float smem[L_TOT];
    float* cfx = ws + OFF_CFX;
    float* cfy = ws + OFF_CFY;
    float* cf0 = ws + OFF_CF0;
    float* stats = ws + OFF_ST;        // s1: [0..63], s2: [64..319]
    short* cwT = (short*)(ws + OFF_CWT);

    const int t = threadIdx.x;
    const int blk = blockIdx.x;
    const int l = t & 63, wv = t >> 6;
    const int lane15 = l & 15, quad = l >> 4;
    const int b = blk >> 5;

    // ======================= phase A: prep + convw =======================
    if (blk == 0) { stats[t] = 0.f; if (t < 64) stats[256 + t] = 0.f; }
    #pragma unroll
    for (int rep = 0; rep < 2; ++rep) {
        int gid = rep*65536 + blk*256 + t;
        if (gid < BB*MM) {
            int bb = gid / MM;
            int m = gid - bb*MM;
            int np = m / 9, k9 = m - np*9;
            float qx = pos[((size_t)(bb*NBB + np))*2 + 0] + kpos[k9*2 + 0];
            float qy = pos[((size_t)(bb*NBB + np))*2 + 1] + kpos[k9*2 + 1];
            cfx[gid] = -2.f*L2C*qx;
            cfy[gid] = -2.f*L2C*qy;
            cf0[gid] = L2C*(qx*qx + qy*qy);
        }
    }
    {
        unsigned short* kwl  = (unsigned short*)(smem + L_SCR);         // 18432 B
        unsigned short* tile = (unsigned short*)(smem + L_SCR) + 9216;  // 2 wave tiles
        // stage kw -> LDS bf16 transposed [k][c][cp]
        for (int u = t; u < KK*CC*CC/4; u += 256) {
            int flat = u*4;
            int row = flat >> 5;
            int c0 = flat & 31;
            int kk = row >> 5, cp = row & 31;
            f32x4 v = *(const f32x4*)&kw[flat];
            kwl[(kk*CC + c0+0)*CC + cp] = f2bf_rne(v.x);
            kwl[(kk*CC + c0+1)*CC + cp] = f2bf_rne(v.y);
            kwl[(kk*CC + c0+2)*CC + cp] = f2bf_rne(v.z);
            kwl[(kk*CC + c0+3)*CC + cp] = f2bf_rne(v.w);
        }
        // B-frag: wts[n][quad*8 .. +7] -> bf16 (wv&1: waves 2,3 load valid dup)
        int nb_ = blk*32 + (wv & 1)*16 + lane15;
        f32x4 w0 = *(const f32x4*)&wts[(size_t)nb_*CC + quad*8];
        f32x4 w1v = *(const f32x4*)&wts[(size_t)nb_*CC + quad*8 + 4];
        union { unsigned short us[8]; short8 s; } bfr;
        bfr.us[0] = f2bf_rne(w0.x);  bfr.us[1] = f2bf_rne(w0.y);
        bfr.us[2] = f2bf_rne(w0.z);  bfr.us[3] = f2bf_rne(w0.w);
        bfr.us[4] = f2bf_rne(w1v.x); bfr.us[5] = f2bf_rne(w1v.y);
        bfr.us[6] = f2bf_rne(w1v.z); bfr.us[7] = f2bf_rne(w1v.w);
        __syncthreads();
        if (wv < 2) {
            f32x4 acc[KK][2];
            #pragma unroll
            for (int kk = 0; kk < KK; ++kk)
                #pragma unroll
                for (int ct = 0; ct < 2; ++ct) {
                    int c = ct*16 + lane15;
                    short8 afr = *(const short8*)&kwl[(kk*CC + c)*CC + quad*8];
                    acc[kk][ct] = __builtin_amdgcn_mfma_f32_16x16x32_bf16(
                        afr, bfr.s, (f32x4)0.f, 0, 0, 0);
                }
            unsigned short* tw = tile + wv*4608;
            #pragma unroll
            for (int kk = 0; kk < KK; ++kk)
                #pragma unroll
                for (int ct = 0; ct < 2; ++ct)
                    #pragma unroll
                    for (int reg = 0; reg < 4; ++reg) {
                        int c = ct*16 + quad*4 + reg;
                        tw[c*144 + lane15*9 + kk] = f2bf_rne(acc[kk][ct][reg]);
                    }
        }
        __syncthreads();
        // writeout: 32 c x 288 m = 1152 short8 over 256 threads
        short* dst = cwT + (size_t)b*CC*MM + (size_t)(blk & 31)*288;
        #pragma unroll
        for (int it = 0; it < 5; ++it) {
            int u = it*256 + t;
            if (u < 1152) {
                int c = u / 36, seg = u - c*36;
                const unsigned short* src = tile + (seg < 18 ? 0 : 4608)
                                          + c*144 + (seg < 18 ? seg : seg - 18)*8;
                short8 v = *(const short8*)src;
                *(short8*)&dst[(size_t)c*MM + seg*8] = v;
            }
        }
    }
    grid_sync(0);

    // ======================= phase B: sample + leaky + s1 ================
    {
        const float* bx = cfx + (size_t)b*MM;
        const float* by = cfy + (size_t)b*MM;
        const float* b0 = cf0 + (size_t)b*MM;
        const short* ca0 = cwT + (size_t)b*CC*MM + (size_t)lane15*MM;
        const short* ca1 = ca0 + (size_t)16*MM;

        float px[2], py[2], cn[2];
        #pragma unroll
        for (int nt = 0; nt < 2; ++nt) {
            int n = blk*32 + nt*16 + lane15;
            float x = pos[(size_t)n*2], y = pos[(size_t)n*2 + 1];
            px[nt] = x; py[nt] = y; cn[nt] = L2C*(x*x + y*y);
        }
        f32x4 acc[2][2];
        acc[0][0] = (f32x4)0.f; acc[0][1] = (f32x4)0.f;
        acc[1][0] = (f32x4)0.f; acc[1][1] = (f32x4)0.f;

        int m0 = wv*2304 + quad*8;
        // manual 1-deep software pipeline (1 wave/SIMD here — hide load latency)
        short8 a0 = *(const short8*)&ca0[m0];
        short8 a1 = *(const short8*)&ca1[m0];
        f32x4 vx0 = *(const f32x4*)&bx[m0], vx1 = *(const f32x4*)&bx[m0+4];
        f32x4 vy0 = *(const f32x4*)&by[m0], vy1 = *(const f32x4*)&by[m0+4];
        f32x4 v00 = *(const f32x4*)&b0[m0], v01 = *(const f32x4*)&b0[m0+4];
        for (int kk = 0; kk < 72; ++kk) {
            int mn = m0 + (kk < 71 ? 32 : 0);
            short8 na0 = *(const short8*)&ca0[mn];
            short8 na1 = *(const short8*)&ca1[mn];
            f32x4 nvx0 = *(const f32x4*)&bx[mn], nvx1 = *(const f32x4*)&bx[mn+4];
            f32x4 nvy0 = *(const f32x4*)&by[mn], nvy1 = *(const f32x4*)&by[mn+4];
            f32x4 nv00 = *(const f32x4*)&b0[mn], nv01 = *(const f32x4*)&b0[mn+4];
            #pragma unroll
            for (int nt = 0; nt < 2; ++nt) {
                f32x2 Xv = {px[nt], px[nt]};
                f32x2 Yv = {py[nt], py[nt]};
                f32x2 Cv = {cn[nt], cn[nt]};
                f32x2 t0 = (f32x2){v00.x, v00.y} + Cv;
                t0 = (f32x2){vy0.x, vy0.y}*Yv + t0;
                t0 = (f32x2){vx0.x, vx0.y}*Xv + t0;
                f32x2 t1 = (f32x2){v00.z, v00.w} + Cv;
                t1 = (f32x2){vy0.z, vy0.w}*Yv + t1;
                t1 = (f32x2){vx0.z, vx0.w}*Xv + t1;
                f32x2 t2 = (f32x2){v01.x, v01.y} + Cv;
                t2 = (f32x2){vy1.x, vy1.y}*Yv + t2;
                t2 = (f32x2){vx1.x, vx1.y}*Xv + t2;
                f32x2 t3 = (f32x2){v01.z, v01.w} + Cv;
                t3 = (f32x2){vy1.z, vy1.w}*Yv + t3;
                t3 = (f32x2){vx1.z, vx1.w}*Xv + t3;
                float e0 = __builtin_amdgcn_exp2f(t0.x);
                float e1 = __builtin_amdgcn_exp2f(t0.y);
                float e2 = __builtin_amdgcn_exp2f(t1.x);
                float e3 = __builtin_amdgcn_exp2f(t1.y);
                float e4 = __builtin_amdgcn_exp2f(t2.x);
                float e5 = __builtin_amdgcn_exp2f(t2.y);
                float e6 = __builtin_amdgcn_exp2f(t3.x);
                float e7 = __builtin_amdgcn_exp2f(t3.y);
                union { unsigned int u[4]; short8 s; } bf;
                bf.u[0] = (__float_as_uint(e0) >> 16) | (__float_as_uint(e1) & 0xffff0000u);
                bf.u[1] = (__float_as_uint(e2) >> 16) | (__float_as_uint(e3) & 0xffff0000u);
                bf.u[2] = (__float_as_uint(e4) >> 16) | (__float_as_uint(e5) & 0xffff0000u);
                bf.u[3] = (__float_as_uint(e6) >> 16) | (__float_as_uint(e7) & 0xffff0000u);
                acc[nt][0] = __builtin_amdgcn_mfma_f32_16x16x32_bf16(a0, bf.s, acc[nt][0], 0, 0, 0);
                acc[nt][1] = __builtin_amdgcn_mfma_f32_16x16x32_bf16(a1, bf.s, acc[nt][1], 0, 0, 0);
            }
            a0 = na0; a1 = na1;
            vx0 = nvx0; vx1 = nvx1; vy0 = nvy0; vy1 = nvy1; v00 = nv00; v01 = nv01;
            m0 = mn;
        }
        // per-wave partials -> LDS red[wv][n][c] (pad 36)
        float* red = smem + L_SCR;
        #pragma unroll
        for (int nt = 0; nt < 2; ++nt)
            #pragma unroll
            for (int ct = 0; ct < 2; ++ct) {
                int n = nt*16 + lane15, c = ct*16 + quad*4;
                *(f32x4*)&red[(wv*32 + n)*36 + c] = acc[nt][ct];
            }
        __syncthreads();
        // reduce 4 waves, leaky, x0->LDS, s1 stats (shfl over 8 n per wave)
        {
            int nr = t >> 3, c0 = (t & 7)*4;
            f32x4 v  = *(const f32x4*)&red[(0*32 + nr)*36 + c0];
            f32x4 v1 = *(const f32x4*)&red[(1*32 + nr)*36 + c0];
            f32x4 v2 = *(const f32x4*)&red[(2*32 + nr)*36 + c0];
            f32x4 v3 = *(const f32x4*)&red[(3*32 + nr)*36 + c0];
            v = v + v1 + v2 + v3;
            v.x = v.x >= 0.f ? v.x : NEG*v.x;
            v.y = v.y >= 0.f ? v.y : NEG*v.y;
            v.z = v.z >= 0.f ? v.z : NEG*v.z;
            v.w = v.w >= 0.f ? v.w : NEG*v.w;
            *(f32x4*)&smem[L_X0 + nr*36 + c0] = v;
            float s0 = v.x, s1v = v.y, s2v = v.z, s3v = v.w;
            float q0 = v.x*v.x, q1 = v.y*v.y, q2 = v.z*v.z, q3 = v.w*v.w;
            #pragma unroll
            for (int mk = 8; mk <= 32; mk <<= 1) {
                s0 += __shfl_xor(s0, mk); s1v += __shfl_xor(s1v, mk);
                s2v += __shfl_xor(s2v, mk); s3v += __shfl_xor(s3v, mk);
                q0 += __shfl_xor(q0, mk); q1 += __shfl_xor(q1, mk);
                q2 += __shfl_xor(q2, mk); q3 += __shfl_xor(q3, mk);
            }
            if (l < 8) {
                atomicAdd(&stats[c0 + 0], s0);  atomicAdd(&stats[c0 + 1], s1v);
                atomicAdd(&stats[c0 + 2], s2v); atomicAdd(&stats[c0 + 3], s3v);
                atomicAdd(&stats[32 + c0 + 0], q0); atomicAdd(&stats[32 + c0 + 1], q1);
                atomicAdd(&stats[32 + c0 + 2], q2); atomicAdd(&stats[32 + c0 + 3], q3);
            }
        }
    }
    grid_sync(1);

    // ======================= phase D: bn1 + mlp1 + s2 ====================
    {
        int nr = t >> 3, c0 = (t & 7)*4;
        f32x4 smv = *(const f32x4*)&stats[c0];
        f32x4 sqv = *(const f32x4*)&stats[32 + c0];
        f32x4 x0v = *(const f32x4*)&smem[L_X0 + nr*36 + c0];
        f32x4 gv = *(const f32x4*)&cg[c0];
        f32x4 bv = *(const f32x4*)&cb[c0];
        f32x4 wv4 = *(const f32x4*)&wts[((size_t)(blk*32 + nr))*CC + c0];
        f32x4 xv;
        #pragma unroll
        for (int i2 = 0; i2 < 4; ++i2) {
            float mu  = smv[i2] * (1.f/NTOT);
            float var = sqv[i2]*(1.f/NTOT) - mu*mu;
            float a   = gv[i2] * rsqrtf(var + EPS);
            xv[i2] = a*(x0v[i2] - mu) + bv[i2] + wv4[i2];
        }
        *(f32x4*)&smem[L_X + nr*36 + c0] = xv;
    }
    __syncthreads();
    {
        int nloc = t & 31, jh2 = (t >> 5) & 1;
        int j0 = wv*32 + jh2*16;
        float acc2[16];
        *(f32x4*)&acc2[0]  = *(const f32x4*)&b1[j0];
        *(f32x4*)&acc2[4]  = *(const f32x4*)&b1[j0 + 4];
        *(f32x4*)&acc2[8]  = *(const f32x4*)&b1[j0 + 8];
        *(f32x4*)&acc2[12] = *(const f32x4*)&b1[j0 + 12];
        #pragma unroll 4
        for (int c = 0; c < 32; ++c) {
            float xc = smem[L_X + nloc*36 + c];
            const float* w1r = W1 + c*CMM + j0;   // 2 addrs/wave -> L1 broadcast
            f32x4 wa = *(const f32x4*)&w1r[0];
            f32x4 wb = *(const f32x4*)&w1r[4];
            f32x4 wc = *(const f32x4*)&w1r[8];
            f32x4 wd = *(const f32x4*)&w1r[12];
            acc2[0]  = fmaf(xc, wa.x, acc2[0]);  acc2[1]  = fmaf(xc, wa.y, acc2[1]);
            acc2[2]  = fmaf(xc, wa.z, acc2[2]);  acc2[3]  = fmaf(xc, wa.w, acc2[3]);
            acc2[4]  = fmaf(xc, wb.x, acc2[4]);  acc2[5]  = fmaf(xc, wb.y, acc2[5]);
            acc2[6]  = fmaf(xc, wb.z, acc2[6]);  acc2[7]  = fmaf(xc, wb.w, acc2[7]);
            acc2[8]  = fmaf(xc, wc.x, acc2[8]);  acc2[9]  = fmaf(xc, wc.y, acc2[9]);
            acc2[10] = fmaf(xc, wc.z, acc2[10]); acc2[11] = fmaf(xc, wc.w, acc2[11]);
            acc2[12] = fmaf(xc, wd.x, acc2[12]); acc2[13] = fmaf(xc, wd.y, acc2[13]);
            acc2[14] = fmaf(xc, wd.z, acc2[14]); acc2[15] = fmaf(xc, wd.w, acc2[15]);
        }
        #pragma unroll
        for (int jj = 0; jj < 16; ++jj)
            acc2[jj] = acc2[jj] >= 0.f ? acc2[jj] : NEG*acc2[jj];
        #pragma unroll
        for (int q = 0; q < 4; ++q)
            *(f32x4*)&smem[L_H0 + nloc*132 + j0 + q*4] = *(f32x4*)&acc2[q*4];
    }
    __syncthreads();
    {
        // s2 stats from LDS h0 transpose: j = t>>1, half over n
        int j = t >> 1, hf = t & 1;
        float ls = 0.f, lq = 0.f;
        #pragma unroll
        for (int i2 = 0; i2 < 16; ++i2) {
            float v = smem[L_H0 + (hf*16 + i2)*132 + j];
            ls += v; lq = fmaf(v, v, lq);
        }
        ls += __shfl_xor(ls, 1); lq += __shfl_xor(lq, 1);
        if (hf == 0) { atomicAdd(&stats[64 + j], ls); atomicAdd(&stats[192 + j], lq); }
    }
    grid_sync(2);

    // ======================= phase E: bn2 + mlp2 + out ===================
    {
        int rid = t >> 5, nl = t & 31;
        int j0e = rid*16;
        float hv[16];
        #pragma unroll
        for (int q = 0; q < 4; ++q)
            *(f32x4*)&hv[q*4] = *(const f32x4*)&smem[L_H0 + nl*132 + j0e + q*4];
        #pragma unroll
        for (int jj = 0; jj < 16; ++jj) {
            int j = j0e + jj;
            float mu  = stats[64 + j] * (1.f/NTOT);
            float var = stats[192 + j]*(1.f/NTOT) - mu*mu;
            float a   = g2[j] * rsqrtf(var + EPS);
            hv[jj] = a*(hv[jj] - mu) + bt2[j];
        }
        float acc3[34];
        #pragma unroll
        for (int c = 0; c < 34; ++c) acc3[c] = 0.f;
        for (int jj = 0; jj < 16; ++jj) {
            float h = hv[jj];
            const float* w2r = W2 + (size_t)(j0e + jj)*34;  // 2 addrs/wave
            #pragma unroll
            for (int c = 0; c < 34; ++c)
                acc3[c] = fmaf(h, w2r[c], acc3[c]);
        }
        float* red2 = smem + L_SCR;   // [8][32][35]
        #pragma unroll
        for (int c = 0; c < 34; ++c) red2[(rid*32 + nl)*35 + c] = acc3[c];
    }
    __syncthreads();
    {
        #pragma unroll
        for (int it = 0; it < 5; ++it) {
            int u = it*256 + t;
            if (u < 1088) {
                int r = u / 34, c = u - r*34;
                float* red2 = smem + L_SCR;
                float v = b2[c];
                #pragma unroll
                for (int rr = 0; rr < 8; ++rr) v += red2[(rr*32 + r)*35 + c];
                int nn = blk*32 + r;
                if (c < 2)
                    out[(size_t)nn*2 + c] = pos[(size_t)nn*2 + c] + v;
                else
                    out[16384 + (size_t)nn*32 + (c-2)] = smem[L_X + r*36 + (c-2)] + v;
            }
        }
    }
}

// ---------------------------------------------------------------------------
extern "C" void kernel_launch(void* const* d_in, const int* in_sizes, int n_in,
                              void* d_out, int out_size, void* d_ws, size_t ws_size,
                              hipStream_t stream) {
    const float* positions = (const float*)d_in[0];
    const float* weights   = (const float*)d_in[1];
    // d_in[2] = batch (int32) — unused, shapes static
    const float* kpos = (const float*)d_in[3];
    const float* kw   = (const float*)d_in[4];
    const float* cg   = (const float*)d_in[5];
    const float* cb   = (const float*)d_in[6];
    const float* W1   = (const float*)d_in[7];
    const float* b1   = (const float*)d_in[8];
    const float* bg   = (const float*)d_in[9];
    const float* bb   = (const float*)d_in[10];
    const float* W2   = (const float*)d_in[11];
    const float* b2   = (const float*)d_in[12];
    float* ws  = (float*)d_ws;
    float* out = (float*)d_out;

    k_fused<<<NBLK, 256, 0, stream>>>(positions, weights, kpos, kw, cg, cb,
                                      W1, b1, bg, bb, W2, b2, ws, out);
}

// Round 3
// 154.124 us; speedup vs baseline: 2.4690x; 2.4690x over previous
//
#include <hip/hip_runtime.h>
#include <hip/hip_bf16.h>

// Problem constants
#define BB    8
#define NBB   1024
#define KK    9
#define CC    32
#define CMM   128
#define NTOT  (BB*NBB)        // 8192
#define MM    (NBB*KK)        // 9216 per batch
#define NEG   0.01f
#define EPS   1e-5f
#define L2C   (-2.8853900817779268f)   /* -2*log2(e) */

// Workspace layout (floats) — part[] eliminated (in-block reduce now)
#define OFF_CWT   0
#define SZ_CWT    (BB*CC*MM/2)            // bf16 in float-slots: 1179648
#define OFF_CFX   (OFF_CWT + SZ_CWT)
#define OFF_CFY   (OFF_CFX + BB*MM)
#define OFF_CF0   (OFF_CFY + BB*MM)
#define OFF_X0    (OFF_CF0 + BB*MM)
#define OFF_X     (OFF_X0 + NTOT*CC)
#define OFF_H0    (OFF_X + NTOT*CC)
#define OFF_ST    (OFF_H0 + NTOT*CMM)     // stats: s1[64] then s2[256]

typedef __attribute__((ext_vector_type(8))) short short8;
typedef __attribute__((ext_vector_type(4))) float f32x4;
typedef __attribute__((ext_vector_type(2))) float f32x2;

static __device__ __forceinline__ unsigned short f2bf_rne(float f) {
    __hip_bfloat16 h = __float2bfloat16(f);
    return *reinterpret_cast<unsigned short*>(&h);
}

// ---------------------------------------------------------------------------
// k_convw (MFMA) + folded prep. grid = 256 (b = blk&7 -> XCD-aligned batch).
//   Block covers 32 n (2 MFMA tiles of 16 n, waves 0-1). All waves stage kw
//   (bf16 transposed [k][c][cp] in LDS), do grid-strided prep, and writeout.
// ---------------------------------------------------------------------------
__global__ __launch_bounds__(256) void k_convw(const float* __restrict__ pos,
                                               const float* __restrict__ kpos,
                                               const float* __restrict__ w,
                                               const float* __restrict__ kw,
                                               float* __restrict__ cfx,
                                               float* __restrict__ cfy,
                                               float* __restrict__ cf0,
                                               float* __restrict__ stats,
                                               short* __restrict__ cwT) {
    __shared__ unsigned short kwl[KK*CC*CC];   // 18 KB  kwT bf16 [k][c][cp]
    __shared__ unsigned short tile[2*32*144];  // 18 KB  2 per-wave tiles
    int t = threadIdx.x;
    int l = t & 63, wv = t >> 6;
    int lane15 = l & 15, quad = l >> 4;
    int blk = blockIdx.x;
    int b = blk & 7, nbl = blk >> 3;           // XCD-aligned batch

    // ---- folded prep: 73728 items over 65536 threads ----
    if (blk == 0 && t < 320) stats[t] = 0.f;
    #pragma unroll
    for (int rep = 0; rep < 2; ++rep) {
        int gid = rep*65536 + blk*256 + t;
        if (gid < BB*MM) {
            int bb = gid / MM;
            int m = gid - bb*MM;
            int np = m / 9, k9 = m - np*9;
            float qx = pos[((size_t)(bb*NBB + np))*2 + 0] + kpos[k9*2 + 0];
            float qy = pos[((size_t)(bb*NBB + np))*2 + 1] + kpos[k9*2 + 1];
            cfx[gid] = -2.f*L2C*qx;
            cfy[gid] = -2.f*L2C*qy;
            cf0[gid] = L2C*(qx*qx + qy*qy);
        }
    }
    // ---- stage kw -> LDS bf16 transposed [k][c][cp] ----
    for (int u = t; u < KK*CC*CC/4; u += 256) {
        int flat = u*4;
        int row = flat >> 5;
        int c0 = flat & 31;
        int kk = row >> 5, cp = row & 31;
        f32x4 v = *(const f32x4*)&kw[flat];
        kwl[(kk*CC + c0+0)*CC + cp] = f2bf_rne(v.x);
        kwl[(kk*CC + c0+1)*CC + cp] = f2bf_rne(v.y);
        kwl[(kk*CC + c0+2)*CC + cp] = f2bf_rne(v.z);
        kwl[(kk*CC + c0+3)*CC + cp] = f2bf_rne(v.w);
    }
    // B-frag: w[n][quad*8 .. +7] -> bf16 (waves 2,3 load valid dup, unused)
    int n = b*NBB + nbl*32 + (wv & 1)*16 + lane15;
    f32x4 w0 = *(const f32x4*)&w[(size_t)n*CC + quad*8];
    f32x4 w1 = *(const f32x4*)&w[(size_t)n*CC + quad*8 + 4];
    union { unsigned short us[8]; short8 s; } bfr;
    bfr.us[0] = f2bf_rne(w0.x); bfr.us[1] = f2bf_rne(w0.y);
    bfr.us[2] = f2bf_rne(w0.z); bfr.us[3] = f2bf_rne(w0.w);
    bfr.us[4] = f2bf_rne(w1.x); bfr.us[5] = f2bf_rne(w1.y);
    bfr.us[6] = f2bf_rne(w1.z); bfr.us[7] = f2bf_rne(w1.w);
    __syncthreads();
    if (wv < 2) {
        f32x4 acc[KK][2];
        #pragma unroll
        for (int kk = 0; kk < KK; ++kk)
            #pragma unroll
            for (int ct = 0; ct < 2; ++ct) {
                int c = ct*16 + lane15;
                short8 afr = *(const short8*)&kwl[(kk*CC + c)*CC + quad*8];
                acc[kk][ct] = __builtin_amdgcn_mfma_f32_16x16x32_bf16(
                    afr, bfr.s, (f32x4)0.f, 0, 0, 0);
            }
        // D: col(n)=lane15, row(c)=quad*4+reg -> tile [c][nloc*9+k]
        unsigned short* tw = tile + wv*4608;
        #pragma unroll
        for (int kk = 0; kk < KK; ++kk)
            #pragma unroll
            for (int ct = 0; ct < 2; ++ct)
                #pragma unroll
                for (int reg = 0; reg < 4; ++reg) {
                    int c = ct*16 + quad*4 + reg;
                    tw[c*144 + lane15*9 + kk] = f2bf_rne(acc[kk][ct][reg]);
                }
    }
    __syncthreads();
    // writeout: 32 c x 288 m = 1152 short8 over 256 threads
    short* dst = cwT + (size_t)b*CC*MM + (size_t)(nbl*32)*9;
    #pragma unroll
    for (int it = 0; it < 5; ++it) {
        int u = it*256 + t;
        if (u < 1152) {
            int c = u / 36, seg = u - c*36;
            const unsigned short* src = tile + (seg < 18 ? 0 : 4608)
                                      + c*144 + (seg < 18 ? seg : seg - 18)*8;
            short8 v = *(const short8*)src;
            *(short8*)&dst[(size_t)c*MM + seg*8] = v;
        }
    }
}

// ---------------------------------------------------------------------------
// k_sample (dominant, MFMA) + in-block reduce + leaky + s1 stats.
// grid = 256 blocks x 1024 threads (16 waves = 4 waves/SIMD, 1 block/CU).
// b = blk&7 (XCD-aligned with k_convw's cwT writes). Block owns 32 n;
// wave wv handles m in [wv*576, wv*576+576) — same inner loop as before.
// 16 partials reduced in LDS; x0 + s1 written directly (part[] eliminated).
// ---------------------------------------------------------------------------
__global__ __launch_bounds__(1024) void k_sample(const float* __restrict__ pos,
                                                 const float* __restrict__ cfx,
                                                 const float* __restrict__ cfy,
                                                 const float* __restrict__ cf0,
                                                 const short* __restrict__ cwT,
                                                 float* __restrict__ x0,
                                                 float* __restrict__ s1) {
    __shared__ float red[16*32*36];   // 72 KB: [wv][n][c] pad 36
    __shared__ float sstat[64];
    int t = threadIdx.x;
    int l = t & 63, wv = t >> 6;
    int blk = blockIdx.x;
    int b = blk & 7, nblk = blk >> 3;
    int lane15 = l & 15, quad = l >> 4;
    int nbase = b*NBB + nblk*32;
    if (t < 64) sstat[t] = 0.f;

    float px[2], py[2], cn[2];
    #pragma unroll
    for (int nt = 0; nt < 2; ++nt) {
        int n = nbase + nt*16 + lane15;
        float x = pos[(size_t)n*2], y = pos[(size_t)n*2 + 1];
        px[nt] = x; py[nt] = y; cn[nt] = L2C*(x*x + y*y);
    }
    f32x4 acc[2][2];
    acc[0][0] = (f32x4)0.f; acc[0][1] = (f32x4)0.f;
    acc[1][0] = (f32x4)0.f; acc[1][1] = (f32x4)0.f;

    const float* bx = cfx + (size_t)b*MM;
    const float* by = cfy + (size_t)b*MM;
    const float* b0 = cf0 + (size_t)b*MM;
    const short* ca0 = cwT + (size_t)b*CC*MM + (size_t)lane15*MM;
    const short* ca1 = ca0 + (size_t)16*MM;

    int m0 = wv*576 + quad*8;
    #pragma unroll 2
    for (int kk = 0; kk < 18; ++kk, m0 += 32) {
        short8 a0 = *(const short8*)&ca0[m0];
        short8 a1 = *(const short8*)&ca1[m0];
        f32x4 vx0 = *(const f32x4*)&bx[m0];
        f32x4 vx1 = *(const f32x4*)&bx[m0 + 4];
        f32x4 vy0 = *(const f32x4*)&by[m0];
        f32x4 vy1 = *(const f32x4*)&by[m0 + 4];
        f32x4 v00 = *(const f32x4*)&b0[m0];
        f32x4 v01 = *(const f32x4*)&b0[m0 + 4];
        #pragma unroll
        for (int nt = 0; nt < 2; ++nt) {
            f32x2 Xv = {px[nt], px[nt]};
            f32x2 Yv = {py[nt], py[nt]};
            f32x2 Cv = {cn[nt], cn[nt]};
            f32x2 t0 = (f32x2){v00.x, v00.y} + Cv;
            t0 = (f32x2){vy0.x, vy0.y}*Yv + t0;
            t0 = (f32x2){vx0.x, vx0.y}*Xv + t0;
            f32x2 t1 = (f32x2){v00.z, v00.w} + Cv;
            t1 = (f32x2){vy0.z, vy0.w}*Yv + t1;
            t1 = (f32x2){vx0.z, vx0.w}*Xv + t1;
            f32x2 t2 = (f32x2){v01.x, v01.y} + Cv;
            t2 = (f32x2){vy1.x, vy1.y}*Yv + t2;
            t2 = (f32x2){vx1.x, vx1.y}*Xv + t2;
            f32x2 t3 = (f32x2){v01.z, v01.w} + Cv;
            t3 = (f32x2){vy1.z, vy1.w}*Yv + t3;
            t3 = (f32x2){vx1.z, vx1.w}*Xv + t3;
            float e0 = __builtin_amdgcn_exp2f(t0.x);
            float e1 = __builtin_amdgcn_exp2f(t0.y);
            float e2 = __builtin_amdgcn_exp2f(t1.x);
            float e3 = __builtin_amdgcn_exp2f(t1.y);
            float e4 = __builtin_amdgcn_exp2f(t2.x);
            float e5 = __builtin_amdgcn_exp2f(t2.y);
            float e6 = __builtin_amdgcn_exp2f(t3.x);
            float e7 = __builtin_amdgcn_exp2f(t3.y);
            union { unsigned int u[4]; short8 s; } bf;
            bf.u[0] = (__float_as_uint(e0) >> 16) | (__float_as_uint(e1) & 0xffff0000u);
            bf.u[1] = (__float_as_uint(e2) >> 16) | (__float_as_uint(e3) & 0xffff0000u);
            bf.u[2] = (__float_as_uint(e4) >> 16) | (__float_as_uint(e5) & 0xffff0000u);
            bf.u[3] = (__float_as_uint(e6) >> 16) | (__float_as_uint(e7) & 0xffff0000u);
            acc[nt][0] = __builtin_amdgcn_mfma_f32_16x16x32_bf16(a0, bf.s, acc[nt][0], 0, 0, 0);
            acc[nt][1] = __builtin_amdgcn_mfma_f32_16x16x32_bf16(a1, bf.s, acc[nt][1], 0, 0, 0);
        }
    }
    // per-wave partials -> LDS red[wv][n][c]
    #pragma unroll
    for (int nt = 0; nt < 2; ++nt)
        #pragma unroll
        for (int ct = 0; ct < 2; ++ct) {
            int n = nt*16 + lane15, c = ct*16 + quad*4;
            *(f32x4*)&red[(wv*32 + n)*36 + c] = acc[nt][ct];
        }
    __syncthreads();
    // reduce 16 partials, leaky, x0 -> global, s1 stats (threads 0..255)
    if (t < 256) {
        int nr = t >> 3, c0 = (t & 7)*4;
        f32x4 v = (f32x4)0.f;
        #pragma unroll
        for (int wp = 0; wp < 16; ++wp)
            v = v + *(const f32x4*)&red[(wp*32 + nr)*36 + c0];
        v.x = v.x >= 0.f ? v.x : NEG*v.x;
        v.y = v.y >= 0.f ? v.y : NEG*v.y;
        v.z = v.z >= 0.f ? v.z : NEG*v.z;
        v.w = v.w >= 0.f ? v.w : NEG*v.w;
        *(f32x4*)&x0[((size_t)(nbase + nr))*CC + c0] = v;
        float s0 = v.x, s1v = v.y, s2v = v.z, s3v = v.w;
        float q0 = v.x*v.x, q1 = v.y*v.y, q2 = v.z*v.z, q3 = v.w*v.w;
        #pragma unroll
        for (int mk = 8; mk <= 32; mk <<= 1) {
            s0 += __shfl_xor(s0, mk); s1v += __shfl_xor(s1v, mk);
            s2v += __shfl_xor(s2v, mk); s3v += __shfl_xor(s3v, mk);
            q0 += __shfl_xor(q0, mk); q1 += __shfl_xor(q1, mk);
            q2 += __shfl_xor(q2, mk); q3 += __shfl_xor(q3, mk);
        }
        if (l < 8) {   // one lane per c0 group per wave (4 waves x 8 lanes)
            atomicAdd(&sstat[c0 + 0], s0);  atomicAdd(&sstat[c0 + 1], s1v);
            atomicAdd(&sstat[c0 + 2], s2v); atomicAdd(&sstat[c0 + 3], s3v);
            atomicAdd(&sstat[32 + c0 + 0], q0); atomicAdd(&sstat[32 + c0 + 1], q1);
            atomicAdd(&sstat[32 + c0 + 2], q2); atomicAdd(&sstat[32 + c0 + 3], q3);
        }
    }
    __syncthreads();
    if (t < 64) atomicAdd(&s1[t], sstat[t]);   // 64 global atomics per block
}

// ---------------------------------------------------------------------------
// k_mlp1: x = bn1(x0) + weights; h0 = leaky(x @ W1 + b1); fused bn2 stats.
// grid = 512: block = 64 n x 32 j (j-quarter). 2 blocks/CU, 2 waves/SIMD.
// ---------------------------------------------------------------------------
__global__ __launch_bounds__(256) void k_mlp1(const float* __restrict__ x0,
                                              const float* __restrict__ wts,
                                              const float* __restrict__ gma,
                                              const float* __restrict__ bta,
                                              const float* __restrict__ W1,
                                              const float* __restrict__ b1,
                                              const float* __restrict__ s1,
                                              float* __restrict__ x,
                                              float* __restrict__ h0,
                                              float* __restrict__ s2) {
    __shared__ float tile[32*68];   // [j_local][n] padded
    int t = threadIdx.x;
    int l = t & 63, wv = t >> 6;
    int blk = blockIdx.x;
    int nb = blk >> 2, jq = blk & 3;
    int n = nb*64 + l;
    int j0 = jq*32 + wv*8;

    float xv[32];
    #pragma unroll
    for (int c = 0; c < 32; ++c) {
        float mu  = s1[c] * (1.f/NTOT);
        float var = s1[32+c]*(1.f/NTOT) - mu*mu;
        float a   = gma[c] * rsqrtf(var + EPS);
        float v   = x0[(size_t)n*CC + c];
        xv[c] = a*(v - mu) + bta[c] + wts[(size_t)n*CC + c];
    }
    if (jq == 0 && wv == 0) {
        #pragma unroll
        for (int c = 0; c < 32; c += 4)
            *(float4*)&x[(size_t)n*CC + c] = make_float4(xv[c], xv[c+1], xv[c+2], xv[c+3]);
    }
    float acc[8];
    *(f32x4*)&acc[0] = *(const f32x4*)&b1[j0];
    *(f32x4*)&acc[4] = *(const f32x4*)&b1[j0 + 4];
    #pragma unroll 8
    for (int c = 0; c < 32; ++c) {
        float xc = xv[c];
        const float* w1r = W1 + c*CMM + j0;   // wave-uniform -> s_load
        f32x4 wa = *(const f32x4*)&w1r[0];
        f32x4 wb = *(const f32x4*)&w1r[4];
        acc[0] = fmaf(xc, wa.x, acc[0]); acc[1] = fmaf(xc, wa.y, acc[1]);
        acc[2] = fmaf(xc, wa.z, acc[2]); acc[3] = fmaf(xc, wa.w, acc[3]);
        acc[4] = fmaf(xc, wb.x, acc[4]); acc[5] = fmaf(xc, wb.y, acc[5]);
        acc[6] = fmaf(xc, wb.z, acc[6]); acc[7] = fmaf(xc, wb.w, acc[7]);
    }
    #pragma unroll
    for (int jj = 0; jj < 8; ++jj) {
        acc[jj] = acc[jj] >= 0.f ? acc[jj] : NEG*acc[jj];
        tile[(wv*8 + jj)*68 + l] = acc[jj];
    }
    float* hd = h0 + (size_t)n*CMM + j0;
    *(float4*)&hd[0] = make_float4(acc[0], acc[1], acc[2], acc[3]);
    *(float4*)&hd[4] = make_float4(acc[4], acc[5], acc[6], acc[7]);
    __syncthreads();
    // stats: thread -> (j_local = t>>3, grp = t&7), 8 n each
    if (t < 256) {
        int jl = t >> 3, grp = t & 7;
        float lsum = 0.f, lsq = 0.f;
        #pragma unroll
        for (int q = 0; q < 2; ++q) {
            f32x4 v = *(const f32x4*)&tile[jl*68 + grp*8 + q*4];
            lsum += v.x + v.y + v.z + v.w;
            lsq = fmaf(v.x, v.x, fmaf(v.y, v.y, fmaf(v.z, v.z, fmaf(v.w, v.w, lsq))));
        }
        lsum += __shfl_xor(lsum, 1); lsq += __shfl_xor(lsq, 1);
        lsum += __shfl_xor(lsum, 2); lsq += __shfl_xor(lsq, 2);
        lsum += __shfl_xor(lsum, 4); lsq += __shfl_xor(lsq, 4);
        if (grp == 0) {
            int jg = jq*32 + jl;
            atomicAdd(&s2[jg], lsum);
            atomicAdd(&s2[CMM + jg], lsq);
        }
    }
}

// ---------------------------------------------------------------------------
// k_mlp2: h = bn2(h0); mlp = h @ W2 + b2; out0 = pos + mlp[:,:2];
//         out1 = x + mlp[:,2:]
// grid = 512: 16 n per block, 16 rid-slices of 8 j, 16-way LDS reduce.
// ---------------------------------------------------------------------------
__global__ __launch_bounds__(256) void k_mlp2(const float* __restrict__ h0,
                                              const float* __restrict__ x,
                                              const float* __restrict__ pos,
                                              const float* __restrict__ g2,
                                              const float* __restrict__ bt2,
                                              const float* __restrict__ W2,
                                              const float* __restrict__ b2,
                                              const float* __restrict__ s2,
                                              float* __restrict__ out) {
    __shared__ float red[16*16*35];   // 35 KB: [rid][n][c]
    int t = threadIdx.x;
    int nl = t & 15, rid = t >> 4;    // rid in [0,16)
    int n = blockIdx.x*16 + nl;
    int j0 = rid*8;
    float hv[8];
    *(f32x4*)&hv[0] = *(const f32x4*)&h0[(size_t)n*CMM + j0];
    *(f32x4*)&hv[4] = *(const f32x4*)&h0[(size_t)n*CMM + j0 + 4];
    #pragma unroll
    for (int jj = 0; jj < 8; ++jj) {
        int j = j0 + jj;
        float mu  = s2[j] * (1.f/NTOT);
        float var = s2[CMM+j]*(1.f/NTOT) - mu*mu;
        float a   = g2[j] * rsqrtf(var + EPS);
        hv[jj] = a*(hv[jj] - mu) + bt2[j];
    }
    float acc[34];
    #pragma unroll
    for (int c = 0; c < 34; ++c) acc[c] = 0.f;
    for (int jj = 0; jj < 8; ++jj) {
        float h = hv[jj];
        const float* w2r = W2 + (size_t)(j0 + jj)*34;
        #pragma unroll
        for (int c = 0; c < 34; ++c)
            acc[c] = fmaf(h, w2r[c], acc[c]);
    }
    #pragma unroll
    for (int c = 0; c < 34; ++c) red[(rid*16 + nl)*35 + c] = acc[c];
    __syncthreads();
    // 16 n x 34 c = 544 outputs over 256 threads
    #pragma unroll
    for (int it = 0; it < 3; ++it) {
        int u = it*256 + t;
        if (u < 544) {
            int r = u / 34, c = u - r*34;
            float v = b2[c];
            #pragma unroll
            for (int rr = 0; rr < 16; ++rr) v += red[(rr*16 + r)*35 + c];
            int nn = blockIdx.x*16 + r;
            if (c < 2)
                out[(size_t)nn*2 + c] = pos[(size_t)nn*2 + c] + v;
            else
                out[16384 + (size_t)nn*32 + (c-2)] = x[(size_t)nn*32 + (c-2)] + v;
        }
    }
}

// ---------------------------------------------------------------------------
extern "C" void kernel_launch(void* const* d_in, const int* in_sizes, int n_in,
                              void* d_out, int out_size, void* d_ws, size_t ws_size,
                              hipStream_t stream) {
    const float* positions = (const float*)d_in[0];
    const float* weights   = (const float*)d_in[1];
    // d_in[2] = batch (int32) — unused, shapes static
    const float* kpos = (const float*)d_in[3];
    const float* kw   = (const float*)d_in[4];
    const float* cg   = (const float*)d_in[5];
    const float* cb   = (const float*)d_in[6];
    const float* W1   = (const float*)d_in[7];
    const float* b1   = (const float*)d_in[8];
    const float* bg   = (const float*)d_in[9];
    const float* bb   = (const float*)d_in[10];
    const float* W2   = (const float*)d_in[11];
    const float* b2   = (const float*)d_in[12];
    float* ws  = (float*)d_ws;
    float* out = (float*)d_out;

    float* s1 = ws + OFF_ST;        // 64 floats
    float* s2 = ws + OFF_ST + 64;   // 256 floats

    k_convw<<<256, 256, 0, stream>>>(positions, kpos, weights, kw,
                                     ws + OFF_CFX, ws + OFF_CFY, ws + OFF_CF0,
                                     s1, (short*)(ws + OFF_CWT));
    k_sample<<<256, 1024, 0, stream>>>(positions, ws + OFF_CFX, ws + OFF_CFY,
                                       ws + OFF_CF0, (const short*)(ws + OFF_CWT),
                                       ws + OFF_X0, s1);
    k_mlp1<<<512, 256, 0, stream>>>(ws + OFF_X0, weights, cg, cb, W1, b1,
                                    s1, ws + OFF_X, ws + OFF_H0, s2);
    k_mlp2<<<512, 256, 0, stream>>>(ws + OFF_H0, ws + OFF_X, positions,
                                    bg, bb, W2, b2, s2, out);
}

// Round 4
// 149.080 us; speedup vs baseline: 2.5525x; 1.0338x over previous
//
#include <hip/hip_runtime.h>
#include <hip/hip_bf16.h>

// Problem constants
#define BB    8
#define NBB   1024
#define KK    9
#define CC    32
#define CMM   128
#define NTOT  (BB*NBB)        // 8192
#define MM    (NBB*KK)        // 9216 per batch
#define NEG   0.01f
#define EPS   1e-5f
#define SQL2  1.6986436f      /* sqrt(2*log2(e)); E = -((s*dx)^2 + (s*dy)^2) */

// Workspace layout (floats)
#define OFF_CWT   0
#define SZ_CWT    (BB*CC*MM/2)            // bf16 in float-slots: 1179648
#define OFF_QPX   (OFF_CWT + SZ_CWT)
#define OFF_QPY   (OFF_QPX + BB*MM)
#define OFF_X0    (OFF_QPY + BB*MM)
#define OFF_X     (OFF_X0 + NTOT*CC)
#define OFF_H0    (OFF_X + NTOT*CC)
#define OFF_ST    (OFF_H0 + NTOT*CMM)     // stats: s1[64] then s2[256]

typedef __attribute__((ext_vector_type(8))) short short8;
typedef __attribute__((ext_vector_type(4))) float f32x4;
typedef __attribute__((ext_vector_type(2))) float f32x2;

static __device__ __forceinline__ unsigned short f2bf_rne(float f) {
    __hip_bfloat16 h = __float2bfloat16(f);
    return *reinterpret_cast<unsigned short*>(&h);
}

// ---------------------------------------------------------------------------
// k_convw (MFMA) + folded prep. grid = 256 (b = blk&7 -> XCD-aligned batch).
//   prep: qpx/qpy = SQL2 * (pos + kpos) per m (8 B/m, cf0 eliminated:
//   E computed as -(dx'^2+dy'^2) in k_sample with free neg modifier).
// ---------------------------------------------------------------------------
__global__ __launch_bounds__(256) void k_convw(const float* __restrict__ pos,
                                               const float* __restrict__ kpos,
                                               const float* __restrict__ w,
                                               const float* __restrict__ kw,
                                               float* __restrict__ qpx,
                                               float* __restrict__ qpy,
                                               float* __restrict__ stats,
                                               short* __restrict__ cwT) {
    __shared__ unsigned short kwl[KK*CC*CC];   // 18 KB  kwT bf16 [k][c][cp]
    __shared__ unsigned short tile[2*32*144];  // 18 KB  2 per-wave tiles
    int t = threadIdx.x;
    int l = t & 63, wv = t >> 6;
    int lane15 = l & 15, quad = l >> 4;
    int blk = blockIdx.x;
    int b = blk & 7, nbl = blk >> 3;           // XCD-aligned batch

    // ---- folded prep: 73728 items over 65536 threads ----
    if (blk == 0 && t < 320) stats[t] = 0.f;
    #pragma unroll
    for (int rep = 0; rep < 2; ++rep) {
        int gid = rep*65536 + blk*256 + t;
        if (gid < BB*MM) {
            int bb = gid / MM;
            int m = gid - bb*MM;
            int np = m / 9, k9 = m - np*9;
            float qx = pos[((size_t)(bb*NBB + np))*2 + 0] + kpos[k9*2 + 0];
            float qy = pos[((size_t)(bb*NBB + np))*2 + 1] + kpos[k9*2 + 1];
            qpx[gid] = SQL2*qx;
            qpy[gid] = SQL2*qy;
        }
    }
    // ---- stage kw -> LDS bf16 transposed [k][c][cp] ----
    for (int u = t; u < KK*CC*CC/4; u += 256) {
        int flat = u*4;
        int row = flat >> 5;
        int c0 = flat & 31;
        int kk = row >> 5, cp = row & 31;
        f32x4 v = *(const f32x4*)&kw[flat];
        kwl[(kk*CC + c0+0)*CC + cp] = f2bf_rne(v.x);
        kwl[(kk*CC + c0+1)*CC + cp] = f2bf_rne(v.y);
        kwl[(kk*CC + c0+2)*CC + cp] = f2bf_rne(v.z);
        kwl[(kk*CC + c0+3)*CC + cp] = f2bf_rne(v.w);
    }
    // B-frag: w[n][quad*8 .. +7] -> bf16 (waves 2,3 load valid dup, unused)
    int n = b*NBB + nbl*32 + (wv & 1)*16 + lane15;
    f32x4 w0 = *(const f32x4*)&w[(size_t)n*CC + quad*8];
    f32x4 w1 = *(const f32x4*)&w[(size_t)n*CC + quad*8 + 4];
    union { unsigned short us[8]; short8 s; } bfr;
    bfr.us[0] = f2bf_rne(w0.x); bfr.us[1] = f2bf_rne(w0.y);
    bfr.us[2] = f2bf_rne(w0.z); bfr.us[3] = f2bf_rne(w0.w);
    bfr.us[4] = f2bf_rne(w1.x); bfr.us[5] = f2bf_rne(w1.y);
    bfr.us[6] = f2bf_rne(w1.z); bfr.us[7] = f2bf_rne(w1.w);
    __syncthreads();
    if (wv < 2) {
        f32x4 acc[KK][2];
        #pragma unroll
        for (int kk = 0; kk < KK; ++kk)
            #pragma unroll
            for (int ct = 0; ct < 2; ++ct) {
                int c = ct*16 + lane15;
                short8 afr = *(const short8*)&kwl[(kk*CC + c)*CC + quad*8];
                acc[kk][ct] = __builtin_amdgcn_mfma_f32_16x16x32_bf16(
                    afr, bfr.s, (f32x4)0.f, 0, 0, 0);
            }
        // D: col(n)=lane15, row(c)=quad*4+reg -> tile [c][nloc*9+k]
        unsigned short* tw = tile + wv*4608;
        #pragma unroll
        for (int kk = 0; kk < KK; ++kk)
            #pragma unroll
            for (int ct = 0; ct < 2; ++ct)
                #pragma unroll
                for (int reg = 0; reg < 4; ++reg) {
                    int c = ct*16 + quad*4 + reg;
                    tw[c*144 + lane15*9 + kk] = f2bf_rne(acc[kk][ct][reg]);
                }
    }
    __syncthreads();
    // writeout: 32 c x 288 m = 1152 short8 over 256 threads
    short* dst = cwT + (size_t)b*CC*MM + (size_t)(nbl*32)*9;
    #pragma unroll
    for (int it = 0; it < 5; ++it) {
        int u = it*256 + t;
        if (u < 1152) {
            int c = u / 36, seg = u - c*36;
            const unsigned short* src = tile + (seg < 18 ? 0 : 4608)
                                      + c*144 + (seg < 18 ? seg : seg - 18)*8;
            short8 v = *(const short8*)src;
            *(short8*)&dst[(size_t)c*MM + seg*8] = v;
        }
    }
}

// ---------------------------------------------------------------------------
// k_sample (dominant, MFMA) + in-block reduce + leaky + s1 stats.
// grid = 256 blocks x 1024 threads (16 waves, 4 waves/SIMD, 1 block/CU).
// Manual 1-deep software pipeline: next iter's 6 loads issued before this
// iter's compute (~200 VALU+exp2 cycles/wave covers L2 latency x4 waves).
// E from scaled q-coords: e = exp2(-(dx'^2+dy'^2)) — neg is a free modifier.
// ---------------------------------------------------------------------------
__global__ __launch_bounds__(1024) void k_sample(const float* __restrict__ pos,
                                                 const float* __restrict__ qpx,
                                                 const float* __restrict__ qpy,
                                                 const short* __restrict__ cwT,
                                                 float* __restrict__ x0,
                                                 float* __restrict__ s1) {
    __shared__ float red[16*32*36];   // 72 KB: [wv][n][c] pad 36
    __shared__ float sstat[64];
    int t = threadIdx.x;
    int l = t & 63, wv = t >> 6;
    int blk = blockIdx.x;
    int b = blk & 7, nblk = blk >> 3;
    int lane15 = l & 15, quad = l >> 4;
    int nbase = b*NBB + nblk*32;
    if (t < 64) sstat[t] = 0.f;

    float px[2], py[2];
    #pragma unroll
    for (int nt = 0; nt < 2; ++nt) {
        int n = nbase + nt*16 + lane15;
        px[nt] = SQL2*pos[(size_t)n*2];
        py[nt] = SQL2*pos[(size_t)n*2 + 1];
    }
    f32x4 acc[2][2];
    acc[0][0] = (f32x4)0.f; acc[0][1] = (f32x4)0.f;
    acc[1][0] = (f32x4)0.f; acc[1][1] = (f32x4)0.f;

    const float* qx = qpx + (size_t)b*MM;
    const float* qy = qpy + (size_t)b*MM;
    const short* ca0 = cwT + (size_t)b*CC*MM + (size_t)lane15*MM;
    const short* ca1 = ca0 + (size_t)16*MM;

    int m0 = wv*576 + quad*8;
    // prologue loads
    short8 a0 = *(const short8*)&ca0[m0];
    short8 a1 = *(const short8*)&ca1[m0];
    f32x4 X0 = *(const f32x4*)&qx[m0], X1 = *(const f32x4*)&qx[m0 + 4];
    f32x4 Y0 = *(const f32x4*)&qy[m0], Y1 = *(const f32x4*)&qy[m0 + 4];
    for (int kk = 0; kk < 18; ++kk) {
        int mn = m0 + (kk < 17 ? 32 : 0);
        // issue next-iteration loads BEFORE compute (1-deep pipeline)
        short8 na0 = *(const short8*)&ca0[mn];
        short8 na1 = *(const short8*)&ca1[mn];
        f32x4 nX0 = *(const f32x4*)&qx[mn], nX1 = *(const f32x4*)&qx[mn + 4];
        f32x4 nY0 = *(const f32x4*)&qy[mn], nY1 = *(const f32x4*)&qy[mn + 4];
        #pragma unroll
        for (int nt = 0; nt < 2; ++nt) {
            f32x2 PX = {px[nt], px[nt]};
            f32x2 PY = {py[nt], py[nt]};
            // packed pairwise |p'-q'|^2 via v_pk ops
            f32x2 dx0 = (f32x2){X0.x, X0.y} - PX;
            f32x2 dy0 = (f32x2){Y0.x, Y0.y} - PY;
            f32x2 t0 = dx0*dx0; t0 = dy0*dy0 + t0;
            f32x2 dx1 = (f32x2){X0.z, X0.w} - PX;
            f32x2 dy1 = (f32x2){Y0.z, Y0.w} - PY;
            f32x2 t1 = dx1*dx1; t1 = dy1*dy1 + t1;
            f32x2 dx2 = (f32x2){X1.x, X1.y} - PX;
            f32x2 dy2 = (f32x2){Y1.x, Y1.y} - PY;
            f32x2 t2 = dx2*dx2; t2 = dy2*dy2 + t2;
            f32x2 dx3 = (f32x2){X1.z, X1.w} - PX;
            f32x2 dy3 = (f32x2){Y1.z, Y1.w} - PY;
            f32x2 t3 = dx3*dx3; t3 = dy3*dy3 + t3;
            float e0 = __builtin_amdgcn_exp2f(-t0.x);
            float e1 = __builtin_amdgcn_exp2f(-t0.y);
            float e2 = __builtin_amdgcn_exp2f(-t1.x);
            float e3 = __builtin_amdgcn_exp2f(-t1.y);
            float e4 = __builtin_amdgcn_exp2f(-t2.x);
            float e5 = __builtin_amdgcn_exp2f(-t2.y);
            float e6 = __builtin_amdgcn_exp2f(-t3.x);
            float e7 = __builtin_amdgcn_exp2f(-t3.y);
            union { unsigned int u[4]; short8 s; } bf;
            bf.u[0] = (__float_as_uint(e0) >> 16) | (__float_as_uint(e1) & 0xffff0000u);
            bf.u[1] = (__float_as_uint(e2) >> 16) | (__float_as_uint(e3) & 0xffff0000u);
            bf.u[2] = (__float_as_uint(e4) >> 16) | (__float_as_uint(e5) & 0xffff0000u);
            bf.u[3] = (__float_as_uint(e6) >> 16) | (__float_as_uint(e7) & 0xffff0000u);
            acc[nt][0] = __builtin_amdgcn_mfma_f32_16x16x32_bf16(a0, bf.s, acc[nt][0], 0, 0, 0);
            acc[nt][1] = __builtin_amdgcn_mfma_f32_16x16x32_bf16(a1, bf.s, acc[nt][1], 0, 0, 0);
        }
        a0 = na0; a1 = na1;
        X0 = nX0; X1 = nX1; Y0 = nY0; Y1 = nY1;
        m0 = mn;
    }
    // per-wave partials -> LDS red[wv][n][c]
    #pragma unroll
    for (int nt = 0; nt < 2; ++nt)
        #pragma unroll
        for (int ct = 0; ct < 2; ++ct) {
            int n = nt*16 + lane15, c = ct*16 + quad*4;
            *(f32x4*)&red[(wv*32 + n)*36 + c] = acc[nt][ct];
        }
    __syncthreads();
    // reduce 16 partials, leaky, x0 -> global, s1 stats (threads 0..255)
    if (t < 256) {
        int nr = t >> 3, c0 = (t & 7)*4;
        f32x4 v = (f32x4)0.f;
        #pragma unroll
        for (int wp = 0; wp < 16; ++wp)
            v = v + *(const f32x4*)&red[(wp*32 + nr)*36 + c0];
        v.x = v.x >= 0.f ? v.x : NEG*v.x;
        v.y = v.y >= 0.f ? v.y : NEG*v.y;
        v.z = v.z >= 0.f ? v.z : NEG*v.z;
        v.w = v.w >= 0.f ? v.w : NEG*v.w;
        *(f32x4*)&x0[((size_t)(nbase + nr))*CC + c0] = v;
        float s0 = v.x, s1v = v.y, s2v = v.z, s3v = v.w;
        float q0 = v.x*v.x, q1 = v.y*v.y, q2 = v.z*v.z, q3 = v.w*v.w;
        #pragma unroll
        for (int mk = 8; mk <= 32; mk <<= 1) {
            s0 += __shfl_xor(s0, mk); s1v += __shfl_xor(s1v, mk);
            s2v += __shfl_xor(s2v, mk); s3v += __shfl_xor(s3v, mk);
            q0 += __shfl_xor(q0, mk); q1 += __shfl_xor(q1, mk);
            q2 += __shfl_xor(q2, mk); q3 += __shfl_xor(q3, mk);
        }
        if (l < 8) {
            atomicAdd(&sstat[c0 + 0], s0);  atomicAdd(&sstat[c0 + 1], s1v);
            atomicAdd(&sstat[c0 + 2], s2v); atomicAdd(&sstat[c0 + 3], s3v);
            atomicAdd(&sstat[32 + c0 + 0], q0); atomicAdd(&sstat[32 + c0 + 1], q1);
            atomicAdd(&sstat[32 + c0 + 2], q2); atomicAdd(&sstat[32 + c0 + 3], q3);
        }
    }
    __syncthreads();
    if (t < 64) atomicAdd(&s1[t], sstat[t]);   // 64 global atomics per block
}

// ---------------------------------------------------------------------------
// k_mlp1: x = bn1(x0) + weights; h0 = leaky(x @ W1 + b1); fused bn2 stats.
// grid = 512: block = 64 n x 32 j (j-quarter). 2 blocks/CU, 2 waves/SIMD.
// ---------------------------------------------------------------------------
__global__ __launch_bounds__(256) void k_mlp1(const float* __restrict__ x0,
                                              const float* __restrict__ wts,
                                              const float* __restrict__ gma,
                                              const float* __restrict__ bta,
                                              const float* __restrict__ W1,
                                              const float* __restrict__ b1,
                                              const float* __restrict__ s1,
                                              float* __restrict__ x,
                                              float* __restrict__ h0,
                                              float* __restrict__ s2) {
    __shared__ float tile[32*68];   // [j_local][n] padded
    int t = threadIdx.x;
    int l = t & 63, wv = t >> 6;
    int blk = blockIdx.x;
    int nb = blk >> 2, jq = blk & 3;
    int n = nb*64 + l;
    int j0 = jq*32 + wv*8;

    float xv[32];
    #pragma unroll
    for (int c = 0; c < 32; ++c) {
        float mu  = s1[c] * (1.f/NTOT);
        float var = s1[32+c]*(1.f/NTOT) - mu*mu;
        float a   = gma[c] * rsqrtf(var + EPS);
        float v   = x0[(size_t)n*CC + c];
        xv[c] = a*(v - mu) + bta[c] + wts[(size_t)n*CC + c];
    }
    if (jq == 0 && wv == 0) {
        #pragma unroll
        for (int c = 0; c < 32; c += 4)
            *(float4*)&x[(size_t)n*CC + c] = make_float4(xv[c], xv[c+1], xv[c+2], xv[c+3]);
    }
    float acc[8];
    *(f32x4*)&acc[0] = *(const f32x4*)&b1[j0];
    *(f32x4*)&acc[4] = *(const f32x4*)&b1[j0 + 4];
    #pragma unroll 8
    for (int c = 0; c < 32; ++c) {
        float xc = xv[c];
        const float* w1r = W1 + c*CMM + j0;   // wave-uniform -> s_load
        f32x4 wa = *(const f32x4*)&w1r[0];
        f32x4 wb = *(const f32x4*)&w1r[4];
        acc[0] = fmaf(xc, wa.x, acc[0]); acc[1] = fmaf(xc, wa.y, acc[1]);
        acc[2] = fmaf(xc, wa.z, acc[2]); acc[3] = fmaf(xc, wa.w, acc[3]);
        acc[4] = fmaf(xc, wb.x, acc[4]); acc[5] = fmaf(xc, wb.y, acc[5]);
        acc[6] = fmaf(xc, wb.z, acc[6]); acc[7] = fmaf(xc, wb.w, acc[7]);
    }
    #pragma unroll
    for (int jj = 0; jj < 8; ++jj) {
        acc[jj] = acc[jj] >= 0.f ? acc[jj] : NEG*acc[jj];
        tile[(wv*8 + jj)*68 + l] = acc[jj];
    }
    float* hd = h0 + (size_t)n*CMM + j0;
    *(float4*)&hd[0] = make_float4(acc[0], acc[1], acc[2], acc[3]);
    *(float4*)&hd[4] = make_float4(acc[4], acc[5], acc[6], acc[7]);
    __syncthreads();
    // stats: thread -> (j_local = t>>3, grp = t&7), 8 n each
    if (t < 256) {
        int jl = t >> 3, grp = t & 7;
        float lsum = 0.f, lsq = 0.f;
        #pragma unroll
        for (int q = 0; q < 2; ++q) {
            f32x4 v = *(const f32x4*)&tile[jl*68 + grp*8 + q*4];
            lsum += v.x + v.y + v.z + v.w;
            lsq = fmaf(v.x, v.x, fmaf(v.y, v.y, fmaf(v.z, v.z, fmaf(v.w, v.w, lsq))));
        }
        lsum += __shfl_xor(lsum, 1); lsq += __shfl_xor(lsq, 1);
        lsum += __shfl_xor(lsum, 2); lsq += __shfl_xor(lsq, 2);
        lsum += __shfl_xor(lsum, 4); lsq += __shfl_xor(lsq, 4);
        if (grp == 0) {
            int jg = jq*32 + jl;
            atomicAdd(&s2[jg], lsum);
            atomicAdd(&s2[CMM + jg], lsq);
        }
    }
}

// ---------------------------------------------------------------------------
// k_mlp2: h = bn2(h0); mlp = h @ W2 + b2; out0 = pos + mlp[:,:2];
//         out1 = x + mlp[:,2:]
// grid = 512: 16 n per block, 16 rid-slices of 8 j, 16-way LDS reduce.
// ---------------------------------------------------------------------------
__global__ __launch_bounds__(256) void k_mlp2(const float* __restrict__ h0,
                                              const float* __restrict__ x,
                                              const float* __restrict__ pos,
                                              const float* __restrict__ g2,
                                              const float* __restrict__ bt2,
                                              const float* __restrict__ W2,
                                              const float* __restrict__ b2,
                                              const float* __restrict__ s2,
                                              float* __restrict__ out) {
    __shared__ float red[16*16*35];   // 35 KB: [rid][n][c]
    int t = threadIdx.x;
    int nl = t & 15, rid = t >> 4;    // rid in [0,16)
    int n = blockIdx.x*16 + nl;
    int j0 = rid*8;
    float hv[8];
    *(f32x4*)&hv[0] = *(const f32x4*)&h0[(size_t)n*CMM + j0];
    *(f32x4*)&hv[4] = *(const f32x4*)&h0[(size_t)n*CMM + j0 + 4];
    #pragma unroll
    for (int jj = 0; jj < 8; ++jj) {
        int j = j0 + jj;
        float mu  = s2[j] * (1.f/NTOT);
        float var = s2[CMM+j]*(1.f/NTOT) - mu*mu;
        float a   = g2[j] * rsqrtf(var + EPS);
        hv[jj] = a*(hv[jj] - mu) + bt2[j];
    }
    float acc[34];
    #pragma unroll
    for (int c = 0; c < 34; ++c) acc[c] = 0.f;
    for (int jj = 0; jj < 8; ++jj) {
        float h = hv[jj];
        const float* w2r = W2 + (size_t)(j0 + jj)*34;
        #pragma unroll
        for (int c = 0; c < 34; ++c)
            acc[c] = fmaf(h, w2r[c], acc[c]);
    }
    #pragma unroll
    for (int c = 0; c < 34; ++c) red[(rid*16 + nl)*35 + c] = acc[c];
    __syncthreads();
    // 16 n x 34 c = 544 outputs over 256 threads
    #pragma unroll
    for (int it = 0; it < 3; ++it) {
        int u = it*256 + t;
        if (u < 544) {
            int r = u / 34, c = u - r*34;
            float v = b2[c];
            #pragma unroll
            for (int rr = 0; rr < 16; ++rr) v += red[(rr*16 + r)*35 + c];
            int nn = blockIdx.x*16 + r;
            if (c < 2)
                out[(size_t)nn*2 + c] = pos[(size_t)nn*2 + c] + v;
            else
                out[16384 + (size_t)nn*32 + (c-2)] = x[(size_t)nn*32 + (c-2)] + v;
        }
    }
}

// ---------------------------------------------------------------------------
extern "C" void kernel_launch(void* const* d_in, const int* in_sizes, int n_in,
                              void* d_out, int out_size, void* d_ws, size_t ws_size,
                              hipStream_t stream) {
    const float* positions = (const float*)d_in[0];
    const float* weights   = (const float*)d_in[1];
    // d_in[2] = batch (int32) — unused, shapes static
    const float* kpos = (const float*)d_in[3];
    const float* kw   = (const float*)d_in[4];
    const float* cg   = (const float*)d_in[5];
    const float* cb   = (const float*)d_in[6];
    const float* W1   = (const float*)d_in[7];
    const float* b1   = (const float*)d_in[8];
    const float* bg   = (const float*)d_in[9];
    const float* bb   = (const float*)d_in[10];
    const float* W2   = (const float*)d_in[11];
    const float* b2   = (const float*)d_in[12];
    float* ws  = (float*)d_ws;
    float* out = (float*)d_out;

    float* s1 = ws + OFF_ST;        // 64 floats
    float* s2 = ws + OFF_ST + 64;   // 256 floats

    k_convw<<<256, 256, 0, stream>>>(positions, kpos, weights, kw,
                                     ws + OFF_QPX, ws + OFF_QPY,
                                     s1, (short*)(ws + OFF_CWT));
    k_sample<<<256, 1024, 0, stream>>>(positions, ws + OFF_QPX, ws + OFF_QPY,
                                       (const short*)(ws + OFF_CWT),
                                       ws + OFF_X0, s1);
    k_mlp1<<<512, 256, 0, stream>>>(ws + OFF_X0, weights, cg, cb, W1, b1,
                                    s1, ws + OFF_X, ws + OFF_H0, s2);
    k_mlp2<<<512, 256, 0, stream>>>(ws + OFF_H0, ws + OFF_X, positions,
                                    bg, bb, W2, b2, s2, out);
}